// Round 2
// baseline (23.637 us; speedup 1.0000x reference)
//
#include <hip/hip_runtime.h>

typedef short short8 __attribute__((ext_vector_type(8)));
typedef float f32x4 __attribute__((ext_vector_type(4)));

static __device__ __forceinline__ unsigned short f2bf(float f) {
    unsigned u = __builtin_bit_cast(unsigned, f);
    u += 0x7FFFu + ((u >> 16) & 1u);   // RNE
    return (unsigned short)(u >> 16);
}

// ws layout:
//   [0,   128K)  Btg   bf16 [256 n][256 k]   (Wp transposed)
//   [128K,256K)  injT  bf16 [8][256 col][32 n] (n=16..31 zero)
//   [256K,288K)  maskW u32  [8][1024]
//   [288K,320K)  rcntW f32  [8][1024]
#define OFF_INJT  (128 * 1024)
#define OFF_MASK  (256 * 1024)
#define OFF_RCNT  (288 * 1024)

// Prep: blocks 0..127   -> inj row (b,n) -> injT bf16 (n=15 also zero-fills n=16..31)
//       blocks 128..143 -> 64x64 transpose tiles of Wp -> bf16 Btg[n][k]
//       blocks 144..151 -> per-pixel mask word + 1/count for batch b
__global__ __launch_bounds__(256)
void prep_kernel(const float* __restrict__ embs,
                 const int* __restrict__ locations,
                 const float* __restrict__ Wp,
                 const float* __restrict__ We,
                 unsigned short* __restrict__ Btg,
                 unsigned short* __restrict__ injT,
                 unsigned* __restrict__ maskW,
                 float* __restrict__ rcntW) {
    __shared__ float sh[64 * 65];
    const int bid = blockIdx.x, t = threadIdx.x;
    if (bid < 128) {
        const int b = bid >> 4, n = bid & 15;
        float e;
        if (n == 15) {
            float s = 0.f;
            #pragma unroll
            for (int j = 0; j < 15; ++j) s += embs[(b * 15 + j) * 256 + t];
            e = s * (1.0f / 15.0f);
        } else {
            e = embs[(b * 15 + n) * 256 + t];
        }
        sh[t] = e;
        __syncthreads();
        float a0 = 0.f, a1 = 0.f, a2 = 0.f, a3 = 0.f;
        #pragma unroll 8
        for (int k0 = 0; k0 < 256; k0 += 4) {
            float4 e4 = *reinterpret_cast<const float4*>(&sh[k0]);
            a0 += e4.x * We[(k0 + 0) * 256 + t];
            a1 += e4.y * We[(k0 + 1) * 256 + t];
            a2 += e4.z * We[(k0 + 2) * 256 + t];
            a3 += e4.w * We[(k0 + 3) * 256 + t];
        }
        float acc = (a0 + a1) + (a2 + a3);
        injT[((size_t)b * 256 + t) * 32 + n] = f2bf(acc);
        if (n == 15) {  // zero the K-pad region n=16..31
            uint4 z = {0, 0, 0, 0};
            uint4* zp = reinterpret_cast<uint4*>(&injT[((size_t)b * 256 + t) * 32 + 16]);
            zp[0] = z; zp[1] = z;
        }
    } else if (bid < 144) {
        const int tt = bid - 128;
        const int kt = (tt >> 2) * 64, n0 = (tt & 3) * 64;
        #pragma unroll
        for (int it = 0; it < 16; ++it) {
            int u = t + it * 256;
            int kl = u >> 6, nl = u & 63;
            sh[kl * 65 + nl] = Wp[(kt + kl) * 256 + n0 + nl];
        }
        __syncthreads();
        #pragma unroll
        for (int it = 0; it < 4; ++it) {
            int v = t + it * 256;
            int nl = v >> 4, kg = v & 15;
            ushort4 o;
            o.x = f2bf(sh[(kg * 4 + 0) * 65 + nl]);
            o.y = f2bf(sh[(kg * 4 + 1) * 65 + nl]);
            o.z = f2bf(sh[(kg * 4 + 2) * 65 + nl]);
            o.w = f2bf(sh[(kg * 4 + 3) * 65 + nl]);
            *reinterpret_cast<ushort4*>(&Btg[(n0 + nl) * 256 + kt + kg * 4]) = o;
        }
    } else {
        const int b = bid - 144;
        const int* loc = locations + b * 60;
        #pragma unroll
        for (int j = 0; j < 4; ++j) {
            int p = t + j * 256;
            int h = p >> 5, w = p & 31;
            unsigned m = 1u << 15;  // full-image box
            #pragma unroll
            for (int nb = 0; nb < 15; ++nb) {
                int y0 = loc[nb * 4 + 0] & ~1;
                int x0 = loc[nb * 4 + 1] & ~1;
                int y1 = (loc[nb * 4 + 2] & ~1) + 2;
                int x1 = (loc[nb * 4 + 3] & ~1) + 2;
                if (h >= y0 && h < y1 && w >= x0 && w < x1) m |= 1u << nb;
            }
            maskW[b * 1024 + p] = m;
            rcntW[b * 1024 + p] = 1.0f / (float)__popc(m);
        }
    }
}

// Fused: NO LDS, NO barriers. Block = 16 pixels x 256 cols, 4 waves (wave = 64 cols).
// proj via 8x4 MFMA from global directly; masked-mean epilogue via 4 more MFMA.
__global__ __launch_bounds__(256)
void fused_kernel(const float* __restrict__ patches,
                  const unsigned short* __restrict__ Btg,
                  const unsigned short* __restrict__ injT,
                  const unsigned* __restrict__ maskW,
                  const float* __restrict__ rcntW,
                  float* __restrict__ out) {
    const int bid = blockIdx.x, t = threadIdx.x;
    const int b = bid >> 6, tile = bid & 63;
    const int p0 = tile * 16;
    const int wv = t >> 6, lane = t & 63, lhi = lane >> 4, llo = lane & 15;
    const int colb = wv * 64;

    // A fragments: row p0+llo, k = ks*32 + lhi*8 (+0..7), f32 -> bf16 in-register
    const float* arow = patches + ((size_t)(b * 1024 + p0 + llo)) * 256;
    short8 af[8];
    #pragma unroll
    for (int ks = 0; ks < 8; ++ks) {
        float4 f0 = *reinterpret_cast<const float4*>(arow + ks * 32 + lhi * 8);
        float4 f1 = *reinterpret_cast<const float4*>(arow + ks * 32 + lhi * 8 + 4);
        short8 a;
        a[0] = (short)f2bf(f0.x); a[1] = (short)f2bf(f0.y);
        a[2] = (short)f2bf(f0.z); a[3] = (short)f2bf(f0.w);
        a[4] = (short)f2bf(f1.x); a[5] = (short)f2bf(f1.y);
        a[6] = (short)f2bf(f1.z); a[7] = (short)f2bf(f1.w);
        af[ks] = a;
    }

    f32x4 acc[4];
    #pragma unroll
    for (int nt = 0; nt < 4; ++nt) acc[nt] = (f32x4){0.f, 0.f, 0.f, 0.f};

    #pragma unroll
    for (int ks = 0; ks < 8; ++ks) {
        #pragma unroll
        for (int nt = 0; nt < 4; ++nt) {
            const short8 bf = *reinterpret_cast<const short8*>(
                Btg + (colb + nt * 16 + llo) * 256 + ks * 32 + lhi * 8);
            acc[nt] = __builtin_amdgcn_mfma_f32_16x16x32_bf16(af[ks], bf, acc[nt], 0, 0, 0);
        }
    }

    // --- epilogue: pooled[p][o] = sum_{n in mask(p)} inj[n][o] via one MFMA layer
    unsigned m = maskW[b * 1024 + p0 + llo];
    short8 mfrag;
    #pragma unroll
    for (int r = 0; r < 8; ++r) {
        int k = lhi * 8 + r;
        mfrag[r] = (k < 16 && ((m >> k) & 1u)) ? (short)0x3F80 : (short)0;
    }
    f32x4 accE[4];
    #pragma unroll
    for (int nt = 0; nt < 4; ++nt) {
        const short8 jf = *reinterpret_cast<const short8*>(
            injT + ((size_t)b * 256 + colb + nt * 16 + llo) * 32 + lhi * 8);
        accE[nt] = __builtin_amdgcn_mfma_f32_16x16x32_bf16(
            mfrag, jf, (f32x4){0.f, 0.f, 0.f, 0.f}, 0, 0, 0);
    }

    float rc[4];
    #pragma unroll
    for (int j = 0; j < 4; ++j) rc[j] = rcntW[b * 1024 + p0 + lhi * 4 + j];

    float* ob = out + ((size_t)b * 1024 + p0) * 256;
    #pragma unroll
    for (int nt = 0; nt < 4; ++nt)
        #pragma unroll
        for (int j = 0; j < 4; ++j)
            ob[(lhi * 4 + j) * 256 + colb + nt * 16 + llo] = acc[nt][j] + rc[j] * accE[nt][j];
}

extern "C" void kernel_launch(void* const* d_in, const int* in_sizes, int n_in,
                              void* d_out, int out_size, void* d_ws, size_t ws_size,
                              hipStream_t stream) {
    const float* patches = (const float*)d_in[0];
    const float* embs    = (const float*)d_in[1];
    const int*   locs    = (const int*)d_in[2];
    const float* Wp      = (const float*)d_in[3];
    const float* We      = (const float*)d_in[4];
    float* out = (float*)d_out;

    unsigned short* Btg   = (unsigned short*)d_ws;
    unsigned short* injT  = (unsigned short*)((char*)d_ws + OFF_INJT);
    unsigned*       maskW = (unsigned*)((char*)d_ws + OFF_MASK);
    float*          rcntW = (float*)((char*)d_ws + OFF_RCNT);

    prep_kernel<<<152, 256, 0, stream>>>(embs, locs, Wp, We, Btg, injT, maskW, rcntW);
    fused_kernel<<<512, 256, 0, stream>>>(patches, Btg, injT, maskW, rcntW, out);
}